// Round 17
// baseline (149.416 us; speedup 1.0000x reference)
//
#include <hip/hip_runtime.h>
#include <math.h>

#define HWp 4096
#define Cp 256
#define Lp 2048
#define Np 3
#define Bp 8

#define OUT_FEAT_N 8388608      // 8*256*4096
#define OUT_BASE_OFF 8388608
#define OUT_REF_OFF 8404992     // + 8*2048
#define NROWS 49152             // 24*2048

// ---- ws byte offsets ----
#define OFF_AF16  ((size_t)0)              // A_f16 [8][2048][256] f16  = 8,388,608 B
#define OFF_BF16  ((size_t)16777216)       // B_f16 [24][2048][256] f16 = 25,165,824 B
#define OFF_PVAL  ((size_t)117440512)      // ppk: 49152*4*2*4 = 1,572,864
#define OFF_BEST  ((size_t)119799808)      // 196,608
#define OFF_CAND2 ((size_t)119996416)      // 196,608
#define OFF_COUNT ((size_t)120193024)      // 4 (pad to 256)
#define OFF_LIST  ((size_t)120193280)      // 196,608
#define OFF_INV   ((size_t)120389888)      // 32*4096*4 = 524,288

typedef _Float16 f16x8 __attribute__((ext_vector_type(8)));
typedef float f32x4 __attribute__((ext_vector_type(4)));

__device__ __forceinline__ unsigned short f16bits(float x){
    union { _Float16 h; unsigned short s; } u;
    u.h = (_Float16)x;
    return u.s;
}

__global__ void init_inv_kernel(int4* __restrict__ inv4){
    int tid = blockIdx.x * blockDim.x + threadIdx.x;   // 32768 int4
    if (tid < 32768) inv4[tid] = make_int4(-1, -1, -1, -1);
}

__global__ void scatter_inv_kernel(const int* __restrict__ refIdxI,
                                   const int* __restrict__ baseIdx,
                                   int* __restrict__ inv){
    int tid = blockIdx.x * blockDim.x + threadIdx.x;   // 65536
    if (tid < NROWS){
        int g = tid >> 11;
        inv[g*4096 + refIdxI[tid]] = tid & 2047;
    } else if (tid < NROWS + Bp*Lp){
        int t = tid - NROWS;
        int b = t >> 11;
        inv[(24 + b)*4096 + baseIdx[t]] = t & 2047;
    }
}

// Transpose-gather (32-hw tiles, 32KB LDS): coalesced reads, in-register ssq,
// shfl-free normalize+store phase.  (R13 configuration, unchanged.)
__global__ __launch_bounds__(256) void gather_kernel(
    const float* __restrict__ feat, const float* __restrict__ refs,
    const int* __restrict__ pindex, const int* __restrict__ inv,
    unsigned char* __restrict__ Af16, unsigned char* __restrict__ Bf16)
{
    int tileh = blockIdx.x & 127;          // 128 tiles of 32 hw
    int g = blockIdx.x >> 7;
    int isRef = (g < 24);
    const float* src;
    int b;
    if (isRef){
        b = g / 3; int r0 = g - b*3; int iv = *pindex;
        int rn = (r0 < iv) ? r0 : r0 + 1;
        src = refs + ((size_t)(b*4 + rn)) * Cp * HWp;
    } else {
        b = g - 24;
        src = feat + (size_t)b * Cp * HWp;
    }
    __shared__ float lds[32 * 256];       // [hw][c], word-xor-swizzled, 32KB
    __shared__ float ssqp[4][32];
    __shared__ float rinv[32];
    int tid = threadIdx.x, hwl = tid & 31, cg = tid >> 5;   // cg 0..7
    int hw0 = tileh * 32;
    const float* sp = src + hw0 + hwl;
    int swz = hwl << 2;
    float* lrow = lds + hwl * 256;
    float ss = 0.f;
    #pragma unroll
    for (int i = 0; i < 8; i++){
        int c0 = cg * 32 + i * 4;
        float x0 = sp[(size_t)(c0 + 0) * HWp];
        float x1 = sp[(size_t)(c0 + 1) * HWp];
        float x2 = sp[(size_t)(c0 + 2) * HWp];
        float x3 = sp[(size_t)(c0 + 3) * HWp];
        ss = fmaf(x0, x0, fmaf(x1, x1, fmaf(x2, x2, fmaf(x3, x3, ss))));
        *(float4*)(lrow + (c0 ^ swz)) = make_float4(x0, x1, x2, x3);
    }
    ss += __shfl_xor(ss, 32, 64);
    int w = tid >> 6, lane = tid & 63;
    if (lane < 32) ssqp[w][lane] = ss;
    __syncthreads();
    if (tid < 32){
        float s = ssqp[0][tid] + ssqp[1][tid] + ssqp[2][tid] + ssqp[3][tid];
        rinv[tid] = 1.0f / fmaxf(sqrtf(s), 1e-12f);
    }
    __syncthreads();
    const int* invg = inv + g * 4096 + hw0;
    unsigned char* dstBase = isRef ? (Bf16 + (size_t)g * Lp * 512)
                                   : (Af16 + (size_t)b * Lp * 512);
    for (int h = w * 8; h < w * 8 + 8; h++){
        int dest = invg[h];
        if (dest < 0) continue;
        float4 v = *(float4*)(lds + h * 256 + ((lane * 4) ^ (h << 2)));
        float rn = rinv[h];
        ushort4 hv;
        hv.x = f16bits(v.x * rn); hv.y = f16bits(v.y * rn);
        hv.z = f16bits(v.z * rn); hv.w = f16bits(v.w * rn);
        *(ushort4*)(dstBase + (size_t)dest * 512 + lane * 8) = hv;
    }
}

// Stage one 16KB B-tile quarter per wave from row-major B_f16 into linear LDS,
// per-lane GLOBAL source (m173 pattern): LDS dest = uniform base + lane*16.
// LDS layout (reader contract): byte d = ks*2048 + ct2*1024 + lane*16 + 2j
// holds B[col = ct2*16 + (lane&15)][k = ks*32 + (lane>>4)*8 + j].
__device__ __forceinline__ void stage4(const unsigned char* srcLane, unsigned char* ldsW){
    #pragma unroll
    for (int p = 0; p < 4; p++)
        __builtin_amdgcn_global_load_lds(
            (const __attribute__((address_space(1))) void*)(srcLane + (p & 1) * 8192 + (p >> 1) * 64),
            (__attribute__((address_space(3))) void*)(ldsW + p * 1024),
            16, 0, 0);
}

// fp16 single-plane A (regs) x B (LDS) MFMA GEMM, 16x16x32, 4 rowsets/wave,
// 4-deep 16KB ring buffers with ONE barrier per phase and counted vmcnt(8)
// (2 stages always in flight; never drained in the loop). Safety: wave skew
// <= 1 phase (next barrier blocks the leader); writer targets buf[(t+2)&3],
// slowest reader touches buf[(t-1)&3] or buf[t&3] -- distinct mod 4.
// Block: 256 thr (4 waves), 256 rows, 16 col-tiles of 32.
__global__ __launch_bounds__(256, 2) void gemm_mfma_kernel(
    const unsigned char* __restrict__ Af16, const unsigned char* __restrict__ Bf16,
    unsigned int* __restrict__ ppk)
{
    // XCD-bijective swizzle (768 blocks, 96/XCD): each XCD owns exactly one b.
    int orig = (blockIdx.x & 7) * 96 + (blockIdx.x >> 3);
    int rowgrp = orig & 7;                 // 8 rowgroups of 256 rows
    int chunk = (orig >> 3) % 12;
    int b = orig / 96;
    int n = chunk >> 2, c4 = chunk & 3;
    int bn = b*3 + n;
    int tid = threadIdx.x, lane = tid & 63, w = tid >> 6;
    int l15 = lane & 15, lg = lane >> 4;   // lg in 0..3

    __shared__ unsigned char bufs[4][16384];

    // ---- A fragments: direct f16 rows, 4 rowsets x 8 ksteps, in VGPRs ----
    int row0 = rowgrp*256 + w*16 + l15;
    const unsigned char* Arow0 = Af16 + ((size_t)b*Lp + row0)*512 + lg*16;
    f32x4 A0[8], A1[8], A2[8], A3[8];
    #pragma unroll
    for (int ks = 0; ks < 8; ks++){
        A0[ks] = *(const f32x4*)(Arow0 + ks*64);
        A1[ks] = *(const f32x4*)(Arow0 + (size_t)64*512 + ks*64);
        A2[ks] = *(const f32x4*)(Arow0 + (size_t)128*512 + ks*64);
        A3[ks] = *(const f32x4*)(Arow0 + (size_t)192*512 + ks*64);
    }
    #pragma unroll
    for (int ks = 0; ks < 8; ks++){
        asm volatile("" : "+v"(A0[ks]), "+v"(A1[ks]), "+v"(A2[ks]), "+v"(A3[ks]));
    }

    // packed top-2 per (rowset, r): 16 sets
    unsigned p1[16], p2[16];
    #pragma unroll
    for (int s = 0; s < 16; s++){ p1[s] = 0u; p2[s] = 0u; }

    // per-lane staging source (unchanged layout)
    const unsigned char* srcLane = Bf16
        + ((size_t)(bn*2048 + c4*512)) * 512
        + l15 * 512 + (lane >> 4) * 16 + w * 128;

    // prologue: 2-deep prefetch
    stage4(srcLane,                 &bufs[0][w*4096]);
    stage4(srcLane + (size_t)16384, &bufs[1][w*4096]);

    #pragma unroll 1
    for (int t = 0; t < 16; t++){
        if (t < 14){
            stage4(srcLane + (size_t)(t+2)*16384, &bufs[(t+2)&3][w*4096]);
            asm volatile("s_waitcnt vmcnt(8)" ::: "memory");
        } else if (t == 14){
            asm volatile("s_waitcnt vmcnt(4)" ::: "memory");
        } else {
            asm volatile("s_waitcnt vmcnt(0)" ::: "memory");
        }
        __builtin_amdgcn_s_barrier();

        const unsigned char* bp = bufs[t & 3];
        f32x4 a00 = {2.f,2.f,2.f,2.f}, a01 = {2.f,2.f,2.f,2.f};
        f32x4 a10 = {2.f,2.f,2.f,2.f}, a11 = {2.f,2.f,2.f,2.f};
        f32x4 a20 = {2.f,2.f,2.f,2.f}, a21 = {2.f,2.f,2.f,2.f};
        f32x4 a30 = {2.f,2.f,2.f,2.f}, a31 = {2.f,2.f,2.f,2.f};
        #pragma unroll
        for (int ks = 0; ks < 8; ks++){
            f16x8 b0 = *(const f16x8*)(bp + ks*2048 + lane*16);
            f16x8 b1 = *(const f16x8*)(bp + ks*2048 + 1024 + lane*16);
            f16x8 a0v = __builtin_bit_cast(f16x8, A0[ks]);
            f16x8 a1v = __builtin_bit_cast(f16x8, A1[ks]);
            f16x8 a2v = __builtin_bit_cast(f16x8, A2[ks]);
            f16x8 a3v = __builtin_bit_cast(f16x8, A3[ks]);
            a00 = __builtin_amdgcn_mfma_f32_16x16x32_f16(a0v, b0, a00, 0, 0, 0);
            a01 = __builtin_amdgcn_mfma_f32_16x16x32_f16(a0v, b1, a01, 0, 0, 0);
            a10 = __builtin_amdgcn_mfma_f32_16x16x32_f16(a1v, b0, a10, 0, 0, 0);
            a11 = __builtin_amdgcn_mfma_f32_16x16x32_f16(a1v, b1, a11, 0, 0, 0);
            a20 = __builtin_amdgcn_mfma_f32_16x16x32_f16(a2v, b0, a20, 0, 0, 0);
            a21 = __builtin_amdgcn_mfma_f32_16x16x32_f16(a2v, b1, a21, 0, 0, 0);
            a30 = __builtin_amdgcn_mfma_f32_16x16x32_f16(a3v, b0, a30, 0, 0, 0);
            a31 = __builtin_amdgcn_mfma_f32_16x16x32_f16(a3v, b1, a31, 0, 0, 0);
        }

        // pack & pairwise top-2; C/D: col = lane&15, row = (lane>>4)*4 + r
        unsigned ci0 = (unsigned)(511 - (t*32 + l15));
        unsigned ci1 = ci0 - 16;
        #pragma unroll
        for (int r = 0; r < 4; r++){
            {
                unsigned u0 = (__float_as_uint(a00[r]) & 0xFFFFFE00u) | ci0;
                unsigned u1 = (__float_as_uint(a01[r]) & 0xFFFFFE00u) | ci1;
                unsigned hi = max(u0, u1), lo = min(u0, u1);
                unsigned tm = min(p1[r], hi);
                p1[r] = max(p1[r], hi);
                p2[r] = max(p2[r], max(lo, tm));
            }
            {
                unsigned u0 = (__float_as_uint(a10[r]) & 0xFFFFFE00u) | ci0;
                unsigned u1 = (__float_as_uint(a11[r]) & 0xFFFFFE00u) | ci1;
                unsigned hi = max(u0, u1), lo = min(u0, u1);
                unsigned tm = min(p1[4+r], hi);
                p1[4+r] = max(p1[4+r], hi);
                p2[4+r] = max(p2[4+r], max(lo, tm));
            }
            {
                unsigned u0 = (__float_as_uint(a20[r]) & 0xFFFFFE00u) | ci0;
                unsigned u1 = (__float_as_uint(a21[r]) & 0xFFFFFE00u) | ci1;
                unsigned hi = max(u0, u1), lo = min(u0, u1);
                unsigned tm = min(p1[8+r], hi);
                p1[8+r] = max(p1[8+r], hi);
                p2[8+r] = max(p2[8+r], max(lo, tm));
            }
            {
                unsigned u0 = (__float_as_uint(a30[r]) & 0xFFFFFE00u) | ci0;
                unsigned u1 = (__float_as_uint(a31[r]) & 0xFFFFFE00u) | ci1;
                unsigned hi = max(u0, u1), lo = min(u0, u1);
                unsigned tm = min(p1[12+r], hi);
                p1[12+r] = max(p1[12+r], hi);
                p2[12+r] = max(p2[12+r], max(lo, tm));
            }
        }
    }

    // merge across 16-lane group per (rowset, r)
    #pragma unroll
    for (int s = 0; s < 16; s++){
        unsigned q1 = p1[s], q2 = p2[s];
        #pragma unroll
        for (int off = 1; off < 16; off <<= 1){
            unsigned o1 = (unsigned)__shfl_xor((int)q1, off, 64);
            unsigned o2 = (unsigned)__shfl_xor((int)q2, off, 64);
            unsigned m1 = max(q1, o1);
            unsigned m2 = max(min(q1, o1), max(q2, o2));
            q1 = m1; q2 = m2;
        }
        if (l15 == 0){
            int rs = s >> 2, r = s & 3;
            size_t grow = (size_t)bn*Lp + rowgrp*256 + rs*64 + w*16 + lg*4 + r;
            size_t slot = grow*4 + c4;
            ppk[slot*2 + 0] = q1;
            ppk[slot*2 + 1] = q2;
        }
    }
}

__global__ void reset_kernel(int* count){ *count = 0; }

__global__ void combine_kernel(const unsigned int* __restrict__ ppk,
                               int* __restrict__ best, int* __restrict__ cand2,
                               float* __restrict__ outF, const int* __restrict__ baseIdx,
                               int* __restrict__ count, int* __restrict__ list)
{
    int gid = blockIdx.x * blockDim.x + threadIdx.x;
    if (gid < NROWS){
        unsigned V1 = 0u, V2 = 0u; int X1 = 0, X2 = 0;
        #pragma unroll
        for (int ch = 0; ch < 4; ch++){
            unsigned u1 = ppk[((size_t)gid*4 + ch)*2 + 0];
            unsigned u2 = ppk[((size_t)gid*4 + ch)*2 + 1];
            unsigned vb1 = u1 & 0xFFFFFE00u; int c1 = ch*512 + 511 - (int)(u1 & 511u);
            unsigned vb2 = u2 & 0xFFFFFE00u; int c2 = ch*512 + 511 - (int)(u2 & 511u);
            if (vb1 > V1 || (vb1 == V1 && c1 < X1)){
                V2 = V1; X2 = X1; V1 = vb1; X1 = c1;
            } else if (vb1 > V2 || (vb1 == V2 && c1 < X2)){
                V2 = vb1; X2 = c1;
            }
            if (vb2 > V2 || (vb2 == V2 && c2 < X2)){ V2 = vb2; X2 = c2; }
        }
        best[gid] = X1; cand2[gid] = X2;
        outF[OUT_REF_OFF + gid] = (float)X1;
        if (__uint_as_float(V1) - __uint_as_float(V2) < 3.6e-4f){
            int s = atomicAdd(count, 1);
            if (s < NROWS) list[s] = gid;
        }
    }
    if (gid < Bp*Lp) outF[OUT_BASE_OFF + gid] = (float)baseIdx[gid];
}

// fp64 re-decision for ambiguous rows from RAW inputs (one wave per row).
__global__ void refine_kernel(const float* __restrict__ feat, const float* __restrict__ refs,
                              const int* __restrict__ baseIdx, const int* __restrict__ refIdxI,
                              const int* __restrict__ pindex,
                              const int* __restrict__ count, const int* __restrict__ list,
                              int* __restrict__ best, const int* __restrict__ cand2,
                              float* __restrict__ outF)
{
    int nf = *count; if (nf > NROWS) nf = NROWS;
    int lane = threadIdx.x & 63;
    int iv = *pindex;
    for (int it = blockIdx.x; it < nf; it += gridDim.x){
        int gid = list[it];
        int bn = gid >> 11, l = gid & 2047;
        int b = bn / 3; int r0 = bn - b*3;
        int rn = (r0 < iv) ? r0 : r0 + 1;
        int i1 = best[gid], i2 = cand2[gid];
        int posA = baseIdx[b*Lp + l];
        int pos1 = refIdxI[bn*Lp + i1];
        int pos2 = refIdxI[bn*Lp + i2];
        const float* fA = feat + (size_t)b * Cp * HWp + posA;
        const float* fR = refs + (size_t)(b*4 + rn) * Cp * HWp;
        const float* f1 = fR + pos1;
        const float* f2 = fR + pos2;
        double s1 = 0, s2 = 0, d1 = 0, d2 = 0;
        #pragma unroll
        for (int j = 0; j < 4; j++){
            int c = lane * 4 + j;
            double a  = (double)fA[(size_t)c * HWp];
            double x1 = (double)f1[(size_t)c * HWp];
            double x2 = (double)f2[(size_t)c * HWp];
            s1 += x1*x1; s2 += x2*x2;
            d1 += a*x1;  d2 += a*x2;
        }
        #pragma unroll
        for (int off = 1; off < 64; off <<= 1){
            s1 += __shfl_xor(s1, off, 64);
            s2 += __shfl_xor(s2, off, 64);
            d1 += __shfl_xor(d1, off, 64);
            d2 += __shfl_xor(d2, off, 64);
        }
        if (lane == 0){
            double q1 = d1 * sqrt(s2), q2 = d2 * sqrt(s1);
            int ix = (q2 > q1 || (q2 == q1 && i2 < i1)) ? i2 : i1;
            best[gid] = ix;
            outF[OUT_REF_OFF + gid] = (float)ix;
        }
    }
}

// Tile-based fuse: load feat tile -> LDS (rotation layout, conflict-free),
// overwrite selected columns with fused values (f16 B rows), write coalesced.
__global__ __launch_bounds__(256) void fuse_tile_kernel(
    const float* __restrict__ feat, const unsigned char* __restrict__ Bf16,
    const int* __restrict__ best, const int* __restrict__ inv,
    const float* __restrict__ sim, const int* __restrict__ pindex,
    float* __restrict__ out)
{
    int tileh = blockIdx.x & 63;
    int b = blockIdx.x >> 6;
    int hw0 = tileh * 64;
    __shared__ float lds[256 * 64];       // addr(c,hw) = c*64 + ((hw + c) & 63)
    int tid = threadIdx.x, hwl = tid & 63, cg = tid >> 6;
    const float* fb = feat + (size_t)b * Cp * HWp + hw0 + hwl;
    #pragma unroll 4
    for (int i = 0; i < 64; i++){
        int c = cg * 64 + i;
        lds[c * 64 + ((hwl + c) & 63)] = fb[(size_t)c * HWp];
    }
    __syncthreads();
    int iv = *pindex;
    float bs  = sim[b*4 + iv];
    float rs0 = sim[b*4 + ((0 < iv) ? 0 : 1)];
    float rs1 = sim[b*4 + ((1 < iv) ? 1 : 2)];
    float rs2 = sim[b*4 + ((2 < iv) ? 2 : 3)];
    int w = cg, lane = tid & 63;
    const int* invg = inv + (24 + b) * 4096 + hw0;
    for (int h = w * 16; h < w * 16 + 16; h++){
        int dest = invg[h];
        if (dest < 0) continue;
        int b0 = best[(b*3 + 0)*Lp + dest];
        int b1 = best[(b*3 + 1)*Lp + dest];
        int b2 = best[(b*3 + 2)*Lp + dest];
        const unsigned char* r0 = Bf16 + ((size_t)(b*3 + 0)*Lp + b0) * 512;
        const unsigned char* r1 = Bf16 + ((size_t)(b*3 + 1)*Lp + b1) * 512;
        const unsigned char* r2 = Bf16 + ((size_t)(b*3 + 2)*Lp + b2) * 512;
        #pragma unroll
        for (int j = 0; j < 4; j++){
            int c = lane + j * 64;
            int la = c * 64 + ((h + c) & 63);
            float base = lds[la];
            float v0 = (float)(*(const _Float16*)(r0 + c*2));
            float v1 = (float)(*(const _Float16*)(r1 + c*2));
            float v2 = (float)(*(const _Float16*)(r2 + c*2));
            lds[la] = bs*base + rs0*v0 + rs1*v1 + rs2*v2;
        }
    }
    __syncthreads();
    float* ob = out + (size_t)b * Cp * HWp + hw0 + hwl;
    #pragma unroll 4
    for (int i = 0; i < 64; i++){
        int c = cg * 64 + i;
        ob[(size_t)c * HWp] = lds[c * 64 + ((hwl + c) & 63)];
    }
}

extern "C" void kernel_launch(void* const* d_in, const int* in_sizes, int n_in,
                              void* d_out, int out_size, void* d_ws, size_t ws_size,
                              hipStream_t stream)
{
    const float* feat    = (const float*)d_in[0];
    const float* refs    = (const float*)d_in[1];
    const float* sim     = (const float*)d_in[2];
    const int*   baseIdx = (const int*)d_in[3];
    const int*   refIdxI = (const int*)d_in[4];
    const int*   pindex  = (const int*)d_in[5];
    float* out = (float*)d_out;
    unsigned char* ws = (unsigned char*)d_ws;

    unsigned char* Af16 = ws + OFF_AF16;
    unsigned char* Bf16 = ws + OFF_BF16;
    unsigned int* ppk = (unsigned int*)(ws + OFF_PVAL);
    int* best  = (int*)(ws + OFF_BEST);
    int* cand2 = (int*)(ws + OFF_CAND2);
    int* count = (int*)(ws + OFF_COUNT);
    int* list  = (int*)(ws + OFF_LIST);
    int* inv   = (int*)(ws + OFF_INV);

    init_inv_kernel<<<128, 256, 0, stream>>>((int4*)inv);
    scatter_inv_kernel<<<256, 256, 0, stream>>>(refIdxI, baseIdx, inv);
    gather_kernel<<<4096, 256, 0, stream>>>(feat, refs, pindex, inv, Af16, Bf16);
    gemm_mfma_kernel<<<768, 256, 0, stream>>>(Af16, Bf16, ppk);
    reset_kernel<<<1, 1, 0, stream>>>(count);
    combine_kernel<<<192, 256, 0, stream>>>(ppk, best, cand2, out, baseIdx, count, list);
    refine_kernel<<<512, 64, 0, stream>>>(feat, refs, baseIdx, refIdxI, pindex, count, list, best, cand2, out);
    fuse_tile_kernel<<<512, 256, 0, stream>>>(feat, Bf16, best, inv, sim, pindex, out);
}

// Round 18
// 145.511 us; speedup vs baseline: 1.0268x; 1.0268x over previous
//
#include <hip/hip_runtime.h>
#include <math.h>

#define HWp 4096
#define Cp 256
#define Lp 2048
#define Np 3
#define Bp 8

#define OUT_FEAT_N 8388608      // 8*256*4096
#define OUT_BASE_OFF 8388608
#define OUT_REF_OFF 8404992     // + 8*2048
#define NROWS 49152             // 24*2048

// ---- ws byte offsets ----
#define OFF_AF16  ((size_t)0)              // A_f16 [8][2048][256] f16  = 8,388,608 B
#define OFF_BF16  ((size_t)16777216)       // B_f16 [24][2048][256] f16 = 25,165,824 B
#define OFF_PVAL  ((size_t)117440512)      // ppk: 49152*4*2*4 = 1,572,864
#define OFF_BEST  ((size_t)119799808)      // 196,608
#define OFF_CAND2 ((size_t)119996416)      // 196,608
#define OFF_COUNT ((size_t)120193024)      // 4 (pad to 256)
#define OFF_LIST  ((size_t)120193280)      // 196,608
#define OFF_INV   ((size_t)120389888)      // 32*4096*4 = 524,288

typedef _Float16 f16x8 __attribute__((ext_vector_type(8)));
typedef float f32x4 __attribute__((ext_vector_type(4)));

__device__ __forceinline__ unsigned short f16bits(float x){
    union { _Float16 h; unsigned short s; } u;
    u.h = (_Float16)x;
    return u.s;
}

__global__ void init_inv_kernel(int4* __restrict__ inv4){
    int tid = blockIdx.x * blockDim.x + threadIdx.x;   // 32768 int4
    if (tid < 32768) inv4[tid] = make_int4(-1, -1, -1, -1);
}

__global__ void scatter_inv_kernel(const int* __restrict__ refIdxI,
                                   const int* __restrict__ baseIdx,
                                   int* __restrict__ inv){
    int tid = blockIdx.x * blockDim.x + threadIdx.x;   // 65536
    if (tid < NROWS){
        int g = tid >> 11;
        inv[g*4096 + refIdxI[tid]] = tid & 2047;
    } else if (tid < NROWS + Bp*Lp){
        int t = tid - NROWS;
        int b = t >> 11;
        inv[(24 + b)*4096 + baseIdx[t]] = t & 2047;
    }
}

// Transpose-gather (32-hw tiles, 32KB LDS): coalesced reads, in-register ssq,
// shfl-free normalize+store phase.  (R13 configuration, unchanged.)
__global__ __launch_bounds__(256) void gather_kernel(
    const float* __restrict__ feat, const float* __restrict__ refs,
    const int* __restrict__ pindex, const int* __restrict__ inv,
    unsigned char* __restrict__ Af16, unsigned char* __restrict__ Bf16)
{
    int tileh = blockIdx.x & 127;          // 128 tiles of 32 hw
    int g = blockIdx.x >> 7;
    int isRef = (g < 24);
    const float* src;
    int b;
    if (isRef){
        b = g / 3; int r0 = g - b*3; int iv = *pindex;
        int rn = (r0 < iv) ? r0 : r0 + 1;
        src = refs + ((size_t)(b*4 + rn)) * Cp * HWp;
    } else {
        b = g - 24;
        src = feat + (size_t)b * Cp * HWp;
    }
    __shared__ float lds[32 * 256];       // [hw][c], word-xor-swizzled, 32KB
    __shared__ float ssqp[4][32];
    __shared__ float rinv[32];
    int tid = threadIdx.x, hwl = tid & 31, cg = tid >> 5;   // cg 0..7
    int hw0 = tileh * 32;
    const float* sp = src + hw0 + hwl;
    int swz = hwl << 2;
    float* lrow = lds + hwl * 256;
    float ss = 0.f;
    #pragma unroll
    for (int i = 0; i < 8; i++){
        int c0 = cg * 32 + i * 4;
        float x0 = sp[(size_t)(c0 + 0) * HWp];
        float x1 = sp[(size_t)(c0 + 1) * HWp];
        float x2 = sp[(size_t)(c0 + 2) * HWp];
        float x3 = sp[(size_t)(c0 + 3) * HWp];
        ss = fmaf(x0, x0, fmaf(x1, x1, fmaf(x2, x2, fmaf(x3, x3, ss))));
        *(float4*)(lrow + (c0 ^ swz)) = make_float4(x0, x1, x2, x3);
    }
    ss += __shfl_xor(ss, 32, 64);
    int w = tid >> 6, lane = tid & 63;
    if (lane < 32) ssqp[w][lane] = ss;
    __syncthreads();
    if (tid < 32){
        float s = ssqp[0][tid] + ssqp[1][tid] + ssqp[2][tid] + ssqp[3][tid];
        rinv[tid] = 1.0f / fmaxf(sqrtf(s), 1e-12f);
    }
    __syncthreads();
    const int* invg = inv + g * 4096 + hw0;
    unsigned char* dstBase = isRef ? (Bf16 + (size_t)g * Lp * 512)
                                   : (Af16 + (size_t)b * Lp * 512);
    for (int h = w * 8; h < w * 8 + 8; h++){
        int dest = invg[h];
        if (dest < 0) continue;
        float4 v = *(float4*)(lds + h * 256 + ((lane * 4) ^ (h << 2)));
        float rn = rinv[h];
        ushort4 hv;
        hv.x = f16bits(v.x * rn); hv.y = f16bits(v.y * rn);
        hv.z = f16bits(v.z * rn); hv.w = f16bits(v.w * rn);
        *(ushort4*)(dstBase + (size_t)dest * 512 + lane * 8) = hv;
    }
}

// Stage one 2KB wave-share (ks = w) of a 16KB B-tile from row-major B_f16
// into linear LDS (m173 pattern): LDS dest = uniform base + lane*16.
// Tile layout (reader contract): byte d = ks*2048 + ct2*1024 + lane*16 + 2j
// holds B[col = ct2*16 + (lane&15)][k = ks*32 + (lane>>4)*8 + j].
__device__ __forceinline__ void stage2(const unsigned char* srcLane, unsigned char* ldsW){
    #pragma unroll
    for (int p = 0; p < 2; p++)
        __builtin_amdgcn_global_load_lds(
            (const __attribute__((address_space(1))) void*)(srcLane + p * 8192),
            (__attribute__((address_space(3))) void*)(ldsW + p * 1024),
            16, 0, 0);
}

// fp16 single-plane A (regs) x B (LDS) MFMA GEMM, 16x16x32.
// 512-thread blocks (8 waves, 2 rowsets each = 256 rows x 512 cols/block):
// same per-CU wave count and per-phase work as R17, but 1 resident block/CU
// so grid 768 packs into EXACTLY 3 rounds (100% slot utilization vs 75%).
// 4-deep 16KB ring, ONE barrier per phase, counted vmcnt (never drained).
__global__ __launch_bounds__(512, 2) void gemm_mfma_kernel(
    const unsigned char* __restrict__ Af16, const unsigned char* __restrict__ Bf16,
    unsigned int* __restrict__ ppk)
{
    // XCD-bijective swizzle (768 blocks, 96/XCD): each XCD owns exactly one b.
    int orig = (blockIdx.x & 7) * 96 + (blockIdx.x >> 3);
    int rowgrp = orig & 7;                 // 8 rowgroups of 256 rows
    int chunk = (orig >> 3) % 12;
    int b = orig / 96;
    int n = chunk >> 2, c4 = chunk & 3;
    int bn = b*3 + n;
    int tid = threadIdx.x, lane = tid & 63, w = tid >> 6;   // w 0..7
    int l15 = lane & 15, lg = lane >> 4;   // lg in 0..3

    __shared__ unsigned char bufs[4][16384];

    // ---- A fragments: direct f16 rows, 2 rowsets x 8 ksteps, in VGPRs ----
    int row0 = rowgrp*256 + w*32 + l15;
    const unsigned char* Arow0 = Af16 + ((size_t)b*Lp + row0)*512 + lg*16;
    const unsigned char* Arow1 = Arow0 + (size_t)16*512;
    f32x4 A0[8], A1[8];
    #pragma unroll
    for (int ks = 0; ks < 8; ks++){
        A0[ks] = *(const f32x4*)(Arow0 + ks*64);
        A1[ks] = *(const f32x4*)(Arow1 + ks*64);
    }
    #pragma unroll
    for (int ks = 0; ks < 8; ks++){
        asm volatile("" : "+v"(A0[ks]), "+v"(A1[ks]));
    }

    // packed top-2 per (rowset, r): 8 sets
    unsigned p1[8], p2[8];
    #pragma unroll
    for (int s = 0; s < 8; s++){ p1[s] = 0u; p2[s] = 0u; }

    // per-lane staging source: wave w stages ks = w (2 loads: p = ct2).
    // byte = (chunk base + t*32 + p*16 + l15)*512 + (w*32 + (l>>4)*8)*2
    const unsigned char* srcLane = Bf16
        + ((size_t)(bn*2048 + c4*512)) * 512
        + l15 * 512 + (lane >> 4) * 16 + w * 64;

    // prologue: 2-deep prefetch (2 loads per wave per tile)
    stage2(srcLane,                 &bufs[0][w*2048]);
    stage2(srcLane + (size_t)16384, &bufs[1][w*2048]);

    #pragma unroll 1
    for (int t = 0; t < 16; t++){
        if (t < 14){
            stage2(srcLane + (size_t)(t+2)*16384, &bufs[(t+2)&3][w*2048]);
            asm volatile("s_waitcnt vmcnt(4)" ::: "memory");
        } else if (t == 14){
            asm volatile("s_waitcnt vmcnt(2)" ::: "memory");
        } else {
            asm volatile("s_waitcnt vmcnt(0)" ::: "memory");
        }
        __builtin_amdgcn_s_barrier();

        const unsigned char* bp = bufs[t & 3];
        f32x4 a00 = {2.f,2.f,2.f,2.f}, a01 = {2.f,2.f,2.f,2.f};
        f32x4 a10 = {2.f,2.f,2.f,2.f}, a11 = {2.f,2.f,2.f,2.f};
        #pragma unroll
        for (int ks = 0; ks < 8; ks++){
            f16x8 b0 = *(const f16x8*)(bp + ks*2048 + lane*16);
            f16x8 b1 = *(const f16x8*)(bp + ks*2048 + 1024 + lane*16);
            f16x8 a0v = __builtin_bit_cast(f16x8, A0[ks]);
            f16x8 a1v = __builtin_bit_cast(f16x8, A1[ks]);
            a00 = __builtin_amdgcn_mfma_f32_16x16x32_f16(a0v, b0, a00, 0, 0, 0);
            a01 = __builtin_amdgcn_mfma_f32_16x16x32_f16(a0v, b1, a01, 0, 0, 0);
            a10 = __builtin_amdgcn_mfma_f32_16x16x32_f16(a1v, b0, a10, 0, 0, 0);
            a11 = __builtin_amdgcn_mfma_f32_16x16x32_f16(a1v, b1, a11, 0, 0, 0);
        }

        // pack & pairwise top-2; C/D: col = lane&15, row = (lane>>4)*4 + r
        unsigned ci0 = (unsigned)(511 - (t*32 + l15));
        unsigned ci1 = ci0 - 16;
        #pragma unroll
        for (int r = 0; r < 4; r++){
            {
                unsigned u0 = (__float_as_uint(a00[r]) & 0xFFFFFE00u) | ci0;
                unsigned u1 = (__float_as_uint(a01[r]) & 0xFFFFFE00u) | ci1;
                unsigned hi = max(u0, u1), lo = min(u0, u1);
                unsigned tm = min(p1[r], hi);
                p1[r] = max(p1[r], hi);
                p2[r] = max(p2[r], max(lo, tm));
            }
            {
                unsigned u0 = (__float_as_uint(a10[r]) & 0xFFFFFE00u) | ci0;
                unsigned u1 = (__float_as_uint(a11[r]) & 0xFFFFFE00u) | ci1;
                unsigned hi = max(u0, u1), lo = min(u0, u1);
                unsigned tm = min(p1[4+r], hi);
                p1[4+r] = max(p1[4+r], hi);
                p2[4+r] = max(p2[4+r], max(lo, tm));
            }
        }
    }

    // merge across 16-lane group per (rowset, r)
    #pragma unroll
    for (int s = 0; s < 8; s++){
        unsigned q1 = p1[s], q2 = p2[s];
        #pragma unroll
        for (int off = 1; off < 16; off <<= 1){
            unsigned o1 = (unsigned)__shfl_xor((int)q1, off, 64);
            unsigned o2 = (unsigned)__shfl_xor((int)q2, off, 64);
            unsigned m1 = max(q1, o1);
            unsigned m2 = max(min(q1, o1), max(q2, o2));
            q1 = m1; q2 = m2;
        }
        if (l15 == 0){
            int rs = s >> 2, r = s & 3;
            size_t grow = (size_t)bn*Lp + rowgrp*256 + w*32 + rs*16 + lg*4 + r;
            size_t slot = grow*4 + c4;
            ppk[slot*2 + 0] = q1;
            ppk[slot*2 + 1] = q2;
        }
    }
}

__global__ void reset_kernel(int* count){ *count = 0; }

__global__ void combine_kernel(const unsigned int* __restrict__ ppk,
                               int* __restrict__ best, int* __restrict__ cand2,
                               float* __restrict__ outF, const int* __restrict__ baseIdx,
                               int* __restrict__ count, int* __restrict__ list)
{
    int gid = blockIdx.x * blockDim.x + threadIdx.x;
    if (gid < NROWS){
        unsigned V1 = 0u, V2 = 0u; int X1 = 0, X2 = 0;
        #pragma unroll
        for (int ch = 0; ch < 4; ch++){
            unsigned u1 = ppk[((size_t)gid*4 + ch)*2 + 0];
            unsigned u2 = ppk[((size_t)gid*4 + ch)*2 + 1];
            unsigned vb1 = u1 & 0xFFFFFE00u; int c1 = ch*512 + 511 - (int)(u1 & 511u);
            unsigned vb2 = u2 & 0xFFFFFE00u; int c2 = ch*512 + 511 - (int)(u2 & 511u);
            if (vb1 > V1 || (vb1 == V1 && c1 < X1)){
                V2 = V1; X2 = X1; V1 = vb1; X1 = c1;
            } else if (vb1 > V2 || (vb1 == V2 && c1 < X2)){
                V2 = vb1; X2 = c1;
            }
            if (vb2 > V2 || (vb2 == V2 && c2 < X2)){ V2 = vb2; X2 = c2; }
        }
        best[gid] = X1; cand2[gid] = X2;
        outF[OUT_REF_OFF + gid] = (float)X1;
        if (__uint_as_float(V1) - __uint_as_float(V2) < 3.6e-4f){
            int s = atomicAdd(count, 1);
            if (s < NROWS) list[s] = gid;
        }
    }
    if (gid < Bp*Lp) outF[OUT_BASE_OFF + gid] = (float)baseIdx[gid];
}

// fp64 re-decision for ambiguous rows from RAW inputs (one wave per row).
__global__ void refine_kernel(const float* __restrict__ feat, const float* __restrict__ refs,
                              const int* __restrict__ baseIdx, const int* __restrict__ refIdxI,
                              const int* __restrict__ pindex,
                              const int* __restrict__ count, const int* __restrict__ list,
                              int* __restrict__ best, const int* __restrict__ cand2,
                              float* __restrict__ outF)
{
    int nf = *count; if (nf > NROWS) nf = NROWS;
    int lane = threadIdx.x & 63;
    int iv = *pindex;
    for (int it = blockIdx.x; it < nf; it += gridDim.x){
        int gid = list[it];
        int bn = gid >> 11, l = gid & 2047;
        int b = bn / 3; int r0 = bn - b*3;
        int rn = (r0 < iv) ? r0 : r0 + 1;
        int i1 = best[gid], i2 = cand2[gid];
        int posA = baseIdx[b*Lp + l];
        int pos1 = refIdxI[bn*Lp + i1];
        int pos2 = refIdxI[bn*Lp + i2];
        const float* fA = feat + (size_t)b * Cp * HWp + posA;
        const float* fR = refs + (size_t)(b*4 + rn) * Cp * HWp;
        const float* f1 = fR + pos1;
        const float* f2 = fR + pos2;
        double s1 = 0, s2 = 0, d1 = 0, d2 = 0;
        #pragma unroll
        for (int j = 0; j < 4; j++){
            int c = lane * 4 + j;
            double a  = (double)fA[(size_t)c * HWp];
            double x1 = (double)f1[(size_t)c * HWp];
            double x2 = (double)f2[(size_t)c * HWp];
            s1 += x1*x1; s2 += x2*x2;
            d1 += a*x1;  d2 += a*x2;
        }
        #pragma unroll
        for (int off = 1; off < 64; off <<= 1){
            s1 += __shfl_xor(s1, off, 64);
            s2 += __shfl_xor(s2, off, 64);
            d1 += __shfl_xor(d1, off, 64);
            d2 += __shfl_xor(d2, off, 64);
        }
        if (lane == 0){
            double q1 = d1 * sqrt(s2), q2 = d2 * sqrt(s1);
            int ix = (q2 > q1 || (q2 == q1 && i2 < i1)) ? i2 : i1;
            best[gid] = ix;
            outF[OUT_REF_OFF + gid] = (float)ix;
        }
    }
}

// Tile-based fuse: load feat tile -> LDS (rotation layout, conflict-free),
// overwrite selected columns with fused values (f16 B rows), write coalesced.
__global__ __launch_bounds__(256) void fuse_tile_kernel(
    const float* __restrict__ feat, const unsigned char* __restrict__ Bf16,
    const int* __restrict__ best, const int* __restrict__ inv,
    const float* __restrict__ sim, const int* __restrict__ pindex,
    float* __restrict__ out)
{
    int tileh = blockIdx.x & 63;
    int b = blockIdx.x >> 6;
    int hw0 = tileh * 64;
    __shared__ float lds[256 * 64];       // addr(c,hw) = c*64 + ((hw + c) & 63)
    int tid = threadIdx.x, hwl = tid & 63, cg = tid >> 6;
    const float* fb = feat + (size_t)b * Cp * HWp + hw0 + hwl;
    #pragma unroll 4
    for (int i = 0; i < 64; i++){
        int c = cg * 64 + i;
        lds[c * 64 + ((hwl + c) & 63)] = fb[(size_t)c * HWp];
    }
    __syncthreads();
    int iv = *pindex;
    float bs  = sim[b*4 + iv];
    float rs0 = sim[b*4 + ((0 < iv) ? 0 : 1)];
    float rs1 = sim[b*4 + ((1 < iv) ? 1 : 2)];
    float rs2 = sim[b*4 + ((2 < iv) ? 2 : 3)];
    int w = cg, lane = tid & 63;
    const int* invg = inv + (24 + b) * 4096 + hw0;
    for (int h = w * 16; h < w * 16 + 16; h++){
        int dest = invg[h];
        if (dest < 0) continue;
        int b0 = best[(b*3 + 0)*Lp + dest];
        int b1 = best[(b*3 + 1)*Lp + dest];
        int b2 = best[(b*3 + 2)*Lp + dest];
        const unsigned char* r0 = Bf16 + ((size_t)(b*3 + 0)*Lp + b0) * 512;
        const unsigned char* r1 = Bf16 + ((size_t)(b*3 + 1)*Lp + b1) * 512;
        const unsigned char* r2 = Bf16 + ((size_t)(b*3 + 2)*Lp + b2) * 512;
        #pragma unroll
        for (int j = 0; j < 4; j++){
            int c = lane + j * 64;
            int la = c * 64 + ((h + c) & 63);
            float base = lds[la];
            float v0 = (float)(*(const _Float16*)(r0 + c*2));
            float v1 = (float)(*(const _Float16*)(r1 + c*2));
            float v2 = (float)(*(const _Float16*)(r2 + c*2));
            lds[la] = bs*base + rs0*v0 + rs1*v1 + rs2*v2;
        }
    }
    __syncthreads();
    float* ob = out + (size_t)b * Cp * HWp + hw0 + hwl;
    #pragma unroll 4
    for (int i = 0; i < 64; i++){
        int c = cg * 64 + i;
        ob[(size_t)c * HWp] = lds[c * 64 + ((hwl + c) & 63)];
    }
}

extern "C" void kernel_launch(void* const* d_in, const int* in_sizes, int n_in,
                              void* d_out, int out_size, void* d_ws, size_t ws_size,
                              hipStream_t stream)
{
    const float* feat    = (const float*)d_in[0];
    const float* refs    = (const float*)d_in[1];
    const float* sim     = (const float*)d_in[2];
    const int*   baseIdx = (const int*)d_in[3];
    const int*   refIdxI = (const int*)d_in[4];
    const int*   pindex  = (const int*)d_in[5];
    float* out = (float*)d_out;
    unsigned char* ws = (unsigned char*)d_ws;

    unsigned char* Af16 = ws + OFF_AF16;
    unsigned char* Bf16 = ws + OFF_BF16;
    unsigned int* ppk = (unsigned int*)(ws + OFF_PVAL);
    int* best  = (int*)(ws + OFF_BEST);
    int* cand2 = (int*)(ws + OFF_CAND2);
    int* count = (int*)(ws + OFF_COUNT);
    int* list  = (int*)(ws + OFF_LIST);
    int* inv   = (int*)(ws + OFF_INV);

    init_inv_kernel<<<128, 256, 0, stream>>>((int4*)inv);
    scatter_inv_kernel<<<256, 256, 0, stream>>>(refIdxI, baseIdx, inv);
    gather_kernel<<<4096, 256, 0, stream>>>(feat, refs, pindex, inv, Af16, Bf16);
    gemm_mfma_kernel<<<768, 512, 0, stream>>>(Af16, Bf16, ppk);
    reset_kernel<<<1, 1, 0, stream>>>(count);
    combine_kernel<<<192, 256, 0, stream>>>(ppk, best, cand2, out, baseIdx, count, list);
    refine_kernel<<<512, 64, 0, stream>>>(feat, refs, baseIdx, refIdxI, pindex, count, list, best, cand2, out);
    fuse_tile_kernel<<<512, 256, 0, stream>>>(feat, Bf16, best, inv, sim, pindex, out);
}